// Round 4
// baseline (499.241 us; speedup 1.0000x reference)
//
#include <hip/hip_runtime.h>

// Volume rotate + trilinear resample + projection along axis 2.
// Round-4 strategy: float2 x-pair pack (134 MB, fits the 256 MB Infinity
// Cache) -> 4x 8B gathers per trilinear sample, all L3-resident.
// (Round 3's float4 pack was 268 MB: overflowed L3 and went HBM-bound.)

#define NN 256

// ---------------- pack kernel ----------------
// v2[z][y][x] = (V[z,y,x], V[z,y,min(x+1,255)])

__global__ __launch_bounds__(256) void pack2_kernel(
    const float* __restrict__ vol, float2* __restrict__ v2)
{
    const int t = blockIdx.x * 256 + threadIdx.x;   // [0, 2^24)
    const int x = t & 255;
    const int x1 = min(x + 1, NN - 1);
    const int rest = t & ~255;
    float2 r;
    r.x = vol[rest | x ];
    r.y = vol[rest | x1];
    v2[t] = r;
}

// ---------------- geometry helpers ----------------

struct RayCtx {
    float bx, by, bz;       // base point of ray
    float r02, r12, r22;    // k direction
};

__device__ __forceinline__ RayCtx make_ray(const float* __restrict__ quats,
                                           int b, int i, int j)
{
    const float q0 = quats[b * 4 + 0];
    const float q1 = quats[b * 4 + 1];
    const float q2 = quats[b * 4 + 2];
    const float q3 = quats[b * 4 + 3];
    const float nrm = sqrtf(q0 * q0 + q1 * q1 + q2 * q2 + q3 * q3);
    const float qw = q0 / nrm, qx = q1 / nrm, qy = q2 / nrm, qz = q3 / nrm;

    const float r00 = 1.0f - 2.0f * (qy * qy + qz * qz);
    const float r01 = 2.0f * (qx * qy - qz * qw);
    const float r02 = 2.0f * (qx * qz + qy * qw);
    const float r10 = 2.0f * (qx * qy + qz * qw);
    const float r11 = 1.0f - 2.0f * (qx * qx + qz * qz);
    const float r12 = 2.0f * (qy * qz - qx * qw);
    const float r20 = 2.0f * (qx * qz - qy * qw);
    const float r21 = 2.0f * (qy * qz + qx * qw);
    const float r22 = 1.0f - 2.0f * (qx * qx + qy * qy);

    const float gi = (float)i - 128.0f;
    const float gj = (float)j - 128.0f;

    RayCtx c;
    c.bx = gi * r00 + gj * r01;
    c.by = gi * r10 + gj * r11;
    c.bz = gi * r20 + gj * r21;
    c.r02 = r02; c.r12 = r12; c.r22 = r22;
    return c;
}

__device__ __forceinline__ void sample_coords(
    const RayCtx& c, int k,
    int& x0, int& y0, int& z0, int& z1,
    float& tfx, float& tfy, float& tfz)
{
    const float half_inv = 1.0f / 128.0f;
    const float gk = (float)k - 128.0f;
    float px = fmaf(gk, c.r02, c.bx) * half_inv;
    float py = fmaf(gk, c.r12, c.by) * half_inv;
    float pz = fmaf(gk, c.r22, c.bz) * half_inv;
    px = fminf(fmaxf(px, -1.0f), 1.0f);
    py = fminf(fmaxf(py, -1.0f), 1.0f);
    pz = fminf(fmaxf(pz, -1.0f), 1.0f);
    px = (px + 1.0f) * 127.5f;
    py = (py + 1.0f) * 127.5f;
    pz = (pz + 1.0f) * 127.5f;

    const float fx = floorf(px), fy = floorf(py), fz = floorf(pz);
    tfx = px - fx; tfy = py - fy; tfz = pz - fz;
    x0 = (int)fx; y0 = (int)fy; z0 = (int)fz;
    z1 = min(z0 + 1, NN - 1);
}

// ---------------- main kernels ----------------

// float2-packed: 4 x 8B gathers per sample, working set L3-resident.
__global__ __launch_bounds__(256) void rotproj2_kernel(
    const float2* __restrict__ v2,
    const float* __restrict__ quats,
    float* __restrict__ out)
{
    const int tx = threadIdx.x, ty = threadIdx.y, tz = threadIdx.z;
    const int b = blockIdx.z;
    const int i = blockIdx.y * 8 + ty;
    const int j = blockIdx.x * 8 + tx;

    const RayCtx c = make_ray(quats, b, i, j);

    float acc = 0.0f;
    const int k0 = tz * 64;
#pragma unroll 8
    for (int kk = 0; kk < 64; ++kk) {
        int x0, y0, z0, z1; float tfx, tfy, tfz;
        sample_coords(c, k0 + kk, x0, y0, z0, z1, tfx, tfy, tfz);
        const int y1 = min(y0 + 1, NN - 1);

        const float2 a0 = v2[(z0 << 16) | (y0 << 8) | x0];
        const float2 a1 = v2[(z0 << 16) | (y1 << 8) | x0];
        const float2 d0 = v2[(z1 << 16) | (y0 << 8) | x0];
        const float2 d1 = v2[(z1 << 16) | (y1 << 8) | x0];

        const float ux = 1.0f - tfx, uy = 1.0f - tfy, uz = 1.0f - tfz;
        const float c00 = a0.x * ux + a0.y * tfx;
        const float c01 = a1.x * ux + a1.y * tfx;
        const float c10 = d0.x * ux + d0.y * tfx;
        const float c11 = d1.x * ux + d1.y * tfx;
        const float c0 = c00 * uy + c01 * tfy;
        const float c1 = c10 * uy + c11 * tfy;
        acc += c0 * uz + c1 * tfz;
    }

    __shared__ float sm[4][8][8];
    sm[tz][ty][tx] = acc;
    __syncthreads();
    if (tz == 0) {
        out[(b << 16) | (i << 8) | j] =
            sm[0][ty][tx] + sm[1][ty][tx] + sm[2][ty][tx] + sm[3][ty][tx];
    }
}

// direct (no packing) fallback — the round-2 passing kernel.
__global__ __launch_bounds__(256) void rotproj_direct_kernel(
    const float* __restrict__ vol,
    const float* __restrict__ quats,
    float* __restrict__ out)
{
    const int tx = threadIdx.x, ty = threadIdx.y, tz = threadIdx.z;
    const int b = blockIdx.z;
    const int i = blockIdx.y * 8 + ty;
    const int j = blockIdx.x * 8 + tx;

    const RayCtx c = make_ray(quats, b, i, j);

    float acc = 0.0f;
    const int k0 = tz * 64;
#pragma unroll 4
    for (int kk = 0; kk < 64; ++kk) {
        int x0, y0, z0, z1; float tfx, tfy, tfz;
        sample_coords(c, k0 + kk, x0, y0, z0, z1, tfx, tfy, tfz);
        const int x1 = min(x0 + 1, NN - 1);
        const int y1 = min(y0 + 1, NN - 1);

        const float* row00 = vol + ((z0 << 16) | (y0 << 8));
        const float* row01 = vol + ((z0 << 16) | (y1 << 8));
        const float* row10 = vol + ((z1 << 16) | (y0 << 8));
        const float* row11 = vol + ((z1 << 16) | (y1 << 8));

        const float v000 = row00[x0], v001 = row00[x1];
        const float v010 = row01[x0], v011 = row01[x1];
        const float v100 = row10[x0], v101 = row10[x1];
        const float v110 = row11[x0], v111 = row11[x1];

        const float ux = 1.0f - tfx, uy = 1.0f - tfy, uz = 1.0f - tfz;
        const float c00 = v000 * ux + v001 * tfx;
        const float c01 = v010 * ux + v011 * tfx;
        const float c10 = v100 * ux + v101 * tfx;
        const float c11 = v110 * ux + v111 * tfx;
        const float c0 = c00 * uy + c01 * tfy;
        const float c1 = c10 * uy + c11 * tfy;
        acc += c0 * uz + c1 * tfz;
    }

    __shared__ float sm[4][8][8];
    sm[tz][ty][tx] = acc;
    __syncthreads();
    if (tz == 0) {
        out[(b << 16) | (i << 8) | j] =
            sm[0][ty][tx] + sm[1][ty][tx] + sm[2][ty][tx] + sm[3][ty][tx];
    }
}

// ---------------- launch ----------------

extern "C" void kernel_launch(void* const* d_in, const int* in_sizes, int n_in,
                              void* d_out, int out_size, void* d_ws, size_t ws_size,
                              hipStream_t stream) {
    const float* vol = (const float*)d_in[0];
    const float* quats = (const float*)d_in[1];
    float* out = (float*)d_out;

    const int B = in_sizes[1] / 4;  // quaternions: (B,4)
    const size_t nvox = (size_t)NN * NN * NN;
    const size_t need2 = nvox * sizeof(float2);   // 134 MB

    dim3 grid(NN / 8, NN / 8, B);
    dim3 block(8, 8, 4);

    if (ws_size >= need2) {
        float2* v2 = (float2*)d_ws;
        const int pack_blocks = (int)(nvox / 256);
        hipLaunchKernelGGL(pack2_kernel, dim3(pack_blocks), dim3(256), 0, stream,
                           vol, v2);
        hipLaunchKernelGGL(rotproj2_kernel, grid, block, 0, stream, v2, quats, out);
    } else {
        hipLaunchKernelGGL(rotproj_direct_kernel, grid, block, 0, stream,
                           vol, quats, out);
    }
}

// Round 6
// 408.103 us; speedup vs baseline: 1.2233x; 1.2233x over previous
//
#include <hip/hip_runtime.h>

// Volume rotate + trilinear resample + projection along axis 2.
// Round-5 (resubmit; prior round lost to GPU acquisition timeout):
// float2 x-pair pack (134 MB, L3-resident) + COMPACT WAVE FOOTPRINT:
// each wave's 64 lanes cover a 4x4x4 (i,j,k) sample sub-brick instead of an
// 8x8x1 patch, shrinking distinct cache-lines probed per divergent gather.
// k-partials per lane (k = 4t+dk) are folded with two shfl_xor ops.

#define NN 256

// ---------------- pack kernel (vectorized) ----------------
// v2[z][y][x] = (V[z,y,x], V[z,y,min(x+1,255)])
// Each thread handles 4 consecutive x: float4 load + 2x float4 store.

__global__ __launch_bounds__(256) void pack2v_kernel(
    const float* __restrict__ vol, float2* __restrict__ v2)
{
    const int t = blockIdx.x * 256 + threadIdx.x;   // [0, 2^24/4)
    const int x4 = (t & 63) << 2;                   // 0,4,...,252
    const int zy = t >> 6;                          // (z<<8)|y
    const int base = (zy << 8) | x4;

    const float4 v = *reinterpret_cast<const float4*>(vol + base);
    const float nxt = (x4 == 252) ? v.w : vol[base + 4];

    float4 lo, hi;
    lo.x = v.x; lo.y = v.y; lo.z = v.y; lo.w = v.z;
    hi.x = v.z; hi.y = v.w; hi.z = v.w; hi.w = nxt;
    float4* dst = reinterpret_cast<float4*>(v2 + base);
    dst[0] = lo;
    dst[1] = hi;
}

// ---------------- geometry helpers ----------------

struct RayCtx {
    float bx, by, bz;       // base point of ray
    float r02, r12, r22;    // k direction
};

__device__ __forceinline__ RayCtx make_ray(const float* __restrict__ quats,
                                           int b, int i, int j)
{
    const float q0 = quats[b * 4 + 0];
    const float q1 = quats[b * 4 + 1];
    const float q2 = quats[b * 4 + 2];
    const float q3 = quats[b * 4 + 3];
    const float nrm = sqrtf(q0 * q0 + q1 * q1 + q2 * q2 + q3 * q3);
    const float qw = q0 / nrm, qx = q1 / nrm, qy = q2 / nrm, qz = q3 / nrm;

    const float r00 = 1.0f - 2.0f * (qy * qy + qz * qz);
    const float r01 = 2.0f * (qx * qy - qz * qw);
    const float r02 = 2.0f * (qx * qz + qy * qw);
    const float r10 = 2.0f * (qx * qy + qz * qw);
    const float r11 = 1.0f - 2.0f * (qx * qx + qz * qz);
    const float r12 = 2.0f * (qy * qz - qx * qw);
    const float r20 = 2.0f * (qx * qz - qy * qw);
    const float r21 = 2.0f * (qy * qz + qx * qw);
    const float r22 = 1.0f - 2.0f * (qx * qx + qy * qy);

    const float gi = (float)i - 128.0f;
    const float gj = (float)j - 128.0f;

    RayCtx c;
    c.bx = gi * r00 + gj * r01;
    c.by = gi * r10 + gj * r11;
    c.bz = gi * r20 + gj * r21;
    c.r02 = r02; c.r12 = r12; c.r22 = r22;
    return c;
}

__device__ __forceinline__ void sample_coords(
    const RayCtx& c, int k,
    int& x0, int& y0, int& z0, int& z1,
    float& tfx, float& tfy, float& tfz)
{
    const float half_inv = 1.0f / 128.0f;
    const float gk = (float)k - 128.0f;
    float px = fmaf(gk, c.r02, c.bx) * half_inv;
    float py = fmaf(gk, c.r12, c.by) * half_inv;
    float pz = fmaf(gk, c.r22, c.bz) * half_inv;
    px = fminf(fmaxf(px, -1.0f), 1.0f);
    py = fminf(fmaxf(py, -1.0f), 1.0f);
    pz = fminf(fmaxf(pz, -1.0f), 1.0f);
    px = (px + 1.0f) * 127.5f;
    py = (py + 1.0f) * 127.5f;
    pz = (pz + 1.0f) * 127.5f;

    const float fx = floorf(px), fy = floorf(py), fz = floorf(pz);
    tfx = px - fx; tfy = py - fy; tfz = pz - fz;
    x0 = (int)fx; y0 = (int)fy; z0 = (int)fz;
    z1 = min(z0 + 1, NN - 1);
}

// ---------------- main kernel: 4x4x4 lane bricks ----------------
// lane l: di = l&3 (i), dj = (l>>2)&3 (j), dk = l>>4 (k residue).
// Wave w of 4 covers quadrant ((w&1)*4, (w>>1)*4) of the block's 8x8 tile.
// Lane partial: sum over k = 4t+dk, t=0..63. Fold dk via shfl_xor(16|32).

__global__ __launch_bounds__(256) void rotproj2c_kernel(
    const float2* __restrict__ v2,
    const float* __restrict__ quats,
    float* __restrict__ out)
{
    const int tid = threadIdx.x;
    const int w = tid >> 6;
    const int l = tid & 63;
    const int di = l & 3;
    const int dj = (l >> 2) & 3;
    const int dk = l >> 4;

    const int b = blockIdx.z;
    const int i = blockIdx.y * 8 + ((w & 1) << 2) + di;
    const int j = blockIdx.x * 8 + ((w >> 1) << 2) + dj;

    const RayCtx c = make_ray(quats, b, i, j);

    float acc = 0.0f;
#pragma unroll 8
    for (int t = 0; t < 64; ++t) {
        const int k = (t << 2) | dk;
        int x0, y0, z0, z1; float tfx, tfy, tfz;
        sample_coords(c, k, x0, y0, z0, z1, tfx, tfy, tfz);
        const int y1 = min(y0 + 1, NN - 1);

        const float2 a0 = v2[(z0 << 16) | (y0 << 8) | x0];
        const float2 a1 = v2[(z0 << 16) | (y1 << 8) | x0];
        const float2 d0 = v2[(z1 << 16) | (y0 << 8) | x0];
        const float2 d1 = v2[(z1 << 16) | (y1 << 8) | x0];

        const float ux = 1.0f - tfx, uy = 1.0f - tfy, uz = 1.0f - tfz;
        const float c00 = a0.x * ux + a0.y * tfx;
        const float c01 = a1.x * ux + a1.y * tfx;
        const float c10 = d0.x * ux + d0.y * tfx;
        const float c11 = d1.x * ux + d1.y * tfx;
        const float c0 = c00 * uy + c01 * tfy;
        const float c1 = c10 * uy + c11 * tfy;
        acc += c0 * uz + c1 * tfz;
    }

    // fold the 4 k-residue partials (lanes differing in dk = bits 4,5)
    acc += __shfl_xor(acc, 16, 64);
    acc += __shfl_xor(acc, 32, 64);
    if (dk == 0) {
        out[(b << 16) | (i << 8) | j] = acc;
    }
}

// ---------------- direct fallback (round-2 proven kernel) ----------------

__global__ __launch_bounds__(256) void rotproj_direct_kernel(
    const float* __restrict__ vol,
    const float* __restrict__ quats,
    float* __restrict__ out)
{
    const int tx = threadIdx.x & 7;
    const int ty = (threadIdx.x >> 3) & 7;
    const int tz = threadIdx.x >> 6;
    const int b = blockIdx.z;
    const int i = blockIdx.y * 8 + ty;
    const int j = blockIdx.x * 8 + tx;

    const RayCtx c = make_ray(quats, b, i, j);

    float acc = 0.0f;
    const int k0 = tz * 64;
#pragma unroll 4
    for (int kk = 0; kk < 64; ++kk) {
        int x0, y0, z0, z1; float tfx, tfy, tfz;
        sample_coords(c, k0 + kk, x0, y0, z0, z1, tfx, tfy, tfz);
        const int x1 = min(x0 + 1, NN - 1);
        const int y1 = min(y0 + 1, NN - 1);

        const float* row00 = vol + ((z0 << 16) | (y0 << 8));
        const float* row01 = vol + ((z0 << 16) | (y1 << 8));
        const float* row10 = vol + ((z1 << 16) | (y0 << 8));
        const float* row11 = vol + ((z1 << 16) | (y1 << 8));

        const float v000 = row00[x0], v001 = row00[x1];
        const float v010 = row01[x0], v011 = row01[x1];
        const float v100 = row10[x0], v101 = row10[x1];
        const float v110 = row11[x0], v111 = row11[x1];

        const float ux = 1.0f - tfx, uy = 1.0f - tfy, uz = 1.0f - tfz;
        const float c00 = v000 * ux + v001 * tfx;
        const float c01 = v010 * ux + v011 * tfx;
        const float c10 = v100 * ux + v101 * tfx;
        const float c11 = v110 * ux + v111 * tfx;
        const float c0 = c00 * uy + c01 * tfy;
        const float c1 = c10 * uy + c11 * tfy;
        acc += c0 * uz + c1 * tfz;
    }

    __shared__ float sm[4][8][8];
    sm[tz][ty][tx] = acc;
    __syncthreads();
    if (tz == 0) {
        out[(b << 16) | (i << 8) | j] =
            sm[0][ty][tx] + sm[1][ty][tx] + sm[2][ty][tx] + sm[3][ty][tx];
    }
}

// ---------------- launch ----------------

extern "C" void kernel_launch(void* const* d_in, const int* in_sizes, int n_in,
                              void* d_out, int out_size, void* d_ws, size_t ws_size,
                              hipStream_t stream) {
    const float* vol = (const float*)d_in[0];
    const float* quats = (const float*)d_in[1];
    float* out = (float*)d_out;

    const int B = in_sizes[1] / 4;  // quaternions: (B,4)
    const size_t nvox = (size_t)NN * NN * NN;
    const size_t need2 = nvox * sizeof(float2);   // 134 MB

    dim3 grid(NN / 8, NN / 8, B);
    dim3 block(256, 1, 1);

    if (ws_size >= need2) {
        float2* v2 = (float2*)d_ws;
        const int pack_blocks = (int)(nvox / 4 / 256);
        hipLaunchKernelGGL(pack2v_kernel, dim3(pack_blocks), dim3(256), 0, stream,
                           vol, v2);
        hipLaunchKernelGGL(rotproj2c_kernel, grid, block, 0, stream, v2, quats, out);
    } else {
        hipLaunchKernelGGL(rotproj_direct_kernel, grid, block, 0, stream,
                           vol, quats, out);
    }
}

// Round 7
// 316.515 us; speedup vs baseline: 1.5773x; 1.2894x over previous
//
#include <hip/hip_runtime.h>
#include <hip/hip_fp16.h>

// Volume rotate + trilinear resample + projection along axis 2.
// Round-7: fp16 4-corner pack (134 MB, L3-resident): v4h[z][y][x] holds the
// four (x,y) corners (x0y0, x1y0, x0y1, x1y1) as 4xfp16 in 8 bytes.
// -> 2 gathers per trilinear sample (z0 and z1 planes) instead of 4.
// Wave keeps the 4x4x4 (i,j,k) compact sample sub-brick from round 6.
// Corners are converted to fp32 BEFORE the lerp chain (no fp16 math).

#define NN 256

// ---------------- helpers ----------------

__device__ __forceinline__ unsigned pack2h(float lo, float hi) {
    __half2 h = __floats2half2_rn(lo, hi);
    return *reinterpret_cast<unsigned*>(&h);
}

__device__ __forceinline__ float2 unpack2h(unsigned u) {
    __half2 h = *reinterpret_cast<__half2*>(&u);
    return __half22float2(h);
}

// ---------------- pack kernel ----------------
// v4h[t], t=(z<<16)|(y<<8)|x : uint2{ lo = (V[z,y,x],V[z,y,x1]) fp16x2,
//                                     hi = (V[z,y1,x],V[z,y1,x1]) fp16x2 }
// Each thread handles 4 consecutive x: 2x float4 row loads + 2 scalars,
// writes 2x uint4 (32B contiguous per thread).

__global__ __launch_bounds__(256) void pack4h_kernel(
    const float* __restrict__ vol, uint2* __restrict__ v4)
{
    const int t = blockIdx.x * 256 + threadIdx.x;   // [0, 2^24/4)
    const int x4 = (t & 63) << 2;                   // 0,4,...,252
    const int zy = t >> 6;                          // (z<<8)|y
    const int y = zy & 255;
    const int y1 = min(y + 1, NN - 1);
    const int z = zy >> 8;

    const float* r0 = vol + ((z << 16) | (y  << 8));
    const float* r1 = vol + ((z << 16) | (y1 << 8));
    const float4 p0 = *reinterpret_cast<const float4*>(r0 + x4);
    const float4 p1 = *reinterpret_cast<const float4*>(r1 + x4);
    const float n0 = (x4 == 252) ? p0.w : r0[x4 + 4];
    const float n1 = (x4 == 252) ? p1.w : r1[x4 + 4];

    uint4 lo, hi;
    lo.x = pack2h(p0.x, p0.y);  lo.y = pack2h(p1.x, p1.y);   // x = x4+0
    lo.z = pack2h(p0.y, p0.z);  lo.w = pack2h(p1.y, p1.z);   // x = x4+1
    hi.x = pack2h(p0.z, p0.w);  hi.y = pack2h(p1.z, p1.w);   // x = x4+2
    hi.z = pack2h(p0.w, n0);    hi.w = pack2h(p1.w, n1);     // x = x4+3

    uint4* dst = reinterpret_cast<uint4*>(v4 + (((size_t)zy << 8) | x4));
    dst[0] = lo;
    dst[1] = hi;
}

// ---------------- geometry helpers ----------------

struct RayCtx {
    float bx, by, bz;       // base point of ray
    float r02, r12, r22;    // k direction
};

__device__ __forceinline__ RayCtx make_ray(const float* __restrict__ quats,
                                           int b, int i, int j)
{
    const float q0 = quats[b * 4 + 0];
    const float q1 = quats[b * 4 + 1];
    const float q2 = quats[b * 4 + 2];
    const float q3 = quats[b * 4 + 3];
    const float nrm = sqrtf(q0 * q0 + q1 * q1 + q2 * q2 + q3 * q3);
    const float qw = q0 / nrm, qx = q1 / nrm, qy = q2 / nrm, qz = q3 / nrm;

    const float r00 = 1.0f - 2.0f * (qy * qy + qz * qz);
    const float r01 = 2.0f * (qx * qy - qz * qw);
    const float r02 = 2.0f * (qx * qz + qy * qw);
    const float r10 = 2.0f * (qx * qy + qz * qw);
    const float r11 = 1.0f - 2.0f * (qx * qx + qz * qz);
    const float r12 = 2.0f * (qy * qz - qx * qw);
    const float r20 = 2.0f * (qx * qz - qy * qw);
    const float r21 = 2.0f * (qy * qz + qx * qw);
    const float r22 = 1.0f - 2.0f * (qx * qx + qy * qy);

    const float gi = (float)i - 128.0f;
    const float gj = (float)j - 128.0f;

    RayCtx c;
    c.bx = gi * r00 + gj * r01;
    c.by = gi * r10 + gj * r11;
    c.bz = gi * r20 + gj * r21;
    c.r02 = r02; c.r12 = r12; c.r22 = r22;
    return c;
}

__device__ __forceinline__ void sample_coords(
    const RayCtx& c, int k,
    int& x0, int& y0, int& z0, int& z1,
    float& tfx, float& tfy, float& tfz)
{
    const float half_inv = 1.0f / 128.0f;
    const float gk = (float)k - 128.0f;
    float px = fmaf(gk, c.r02, c.bx) * half_inv;
    float py = fmaf(gk, c.r12, c.by) * half_inv;
    float pz = fmaf(gk, c.r22, c.bz) * half_inv;
    px = fminf(fmaxf(px, -1.0f), 1.0f);
    py = fminf(fmaxf(py, -1.0f), 1.0f);
    pz = fminf(fmaxf(pz, -1.0f), 1.0f);
    px = (px + 1.0f) * 127.5f;
    py = (py + 1.0f) * 127.5f;
    pz = (pz + 1.0f) * 127.5f;

    const float fx = floorf(px), fy = floorf(py), fz = floorf(pz);
    tfx = px - fx; tfy = py - fy; tfz = pz - fz;
    x0 = (int)fx; y0 = (int)fy; z0 = (int)fz;
    z1 = min(z0 + 1, NN - 1);
}

// ---------------- main kernel: 4x4x4 lane bricks, 2 gathers/sample ----------
// lane l: di = l&3 (i), dj = (l>>2)&3 (j), dk = l>>4 (k residue).
// Wave w of 4 covers quadrant ((w&1)*4, (w>>1)*4) of the block's 8x8 tile.
// Lane partial: sum over k = 4t+dk, t=0..63. Fold dk via shfl_xor(16|32).

__global__ __launch_bounds__(256) void rotproj4h_kernel(
    const uint2* __restrict__ v4,
    const float* __restrict__ quats,
    float* __restrict__ out)
{
    const int tid = threadIdx.x;
    const int w = tid >> 6;
    const int l = tid & 63;
    const int di = l & 3;
    const int dj = (l >> 2) & 3;
    const int dk = l >> 4;

    const int b = blockIdx.z;
    const int i = blockIdx.y * 8 + ((w & 1) << 2) + di;
    const int j = blockIdx.x * 8 + ((w >> 1) << 2) + dj;

    const RayCtx c = make_ray(quats, b, i, j);

    float acc = 0.0f;
#pragma unroll 8
    for (int t = 0; t < 64; ++t) {
        const int k = (t << 2) | dk;
        int x0, y0, z0, z1; float tfx, tfy, tfz;
        sample_coords(c, k, x0, y0, z0, z1, tfx, tfy, tfz);

        const uint2 A = v4[(z0 << 16) | (y0 << 8) | x0];
        const uint2 D = v4[(z1 << 16) | (y0 << 8) | x0];

        const float2 a0 = unpack2h(A.x);   // (z0,y0,x0), (z0,y0,x1)
        const float2 a1 = unpack2h(A.y);   // (z0,y1,x0), (z0,y1,x1)
        const float2 d0 = unpack2h(D.x);   // (z1,y0,*)
        const float2 d1 = unpack2h(D.y);   // (z1,y1,*)

        const float ux = 1.0f - tfx, uy = 1.0f - tfy, uz = 1.0f - tfz;
        const float c00 = a0.x * ux + a0.y * tfx;
        const float c01 = a1.x * ux + a1.y * tfx;
        const float c10 = d0.x * ux + d0.y * tfx;
        const float c11 = d1.x * ux + d1.y * tfx;
        const float c0 = c00 * uy + c01 * tfy;
        const float c1 = c10 * uy + c11 * tfy;
        acc += c0 * uz + c1 * tfz;
    }

    // fold the 4 k-residue partials (lanes differing in dk = bits 4,5)
    acc += __shfl_xor(acc, 16, 64);
    acc += __shfl_xor(acc, 32, 64);
    if (dk == 0) {
        out[(b << 16) | (i << 8) | j] = acc;
    }
}

// ---------------- direct fallback (round-2 proven kernel) ----------------

__global__ __launch_bounds__(256) void rotproj_direct_kernel(
    const float* __restrict__ vol,
    const float* __restrict__ quats,
    float* __restrict__ out)
{
    const int tx = threadIdx.x & 7;
    const int ty = (threadIdx.x >> 3) & 7;
    const int tz = threadIdx.x >> 6;
    const int b = blockIdx.z;
    const int i = blockIdx.y * 8 + ty;
    const int j = blockIdx.x * 8 + tx;

    const RayCtx c = make_ray(quats, b, i, j);

    float acc = 0.0f;
    const int k0 = tz * 64;
#pragma unroll 4
    for (int kk = 0; kk < 64; ++kk) {
        int x0, y0, z0, z1; float tfx, tfy, tfz;
        sample_coords(c, k0 + kk, x0, y0, z0, z1, tfx, tfy, tfz);
        const int x1 = min(x0 + 1, NN - 1);
        const int y1 = min(y0 + 1, NN - 1);

        const float* row00 = vol + ((z0 << 16) | (y0 << 8));
        const float* row01 = vol + ((z0 << 16) | (y1 << 8));
        const float* row10 = vol + ((z1 << 16) | (y0 << 8));
        const float* row11 = vol + ((z1 << 16) | (y1 << 8));

        const float v000 = row00[x0], v001 = row00[x1];
        const float v010 = row01[x0], v011 = row01[x1];
        const float v100 = row10[x0], v101 = row10[x1];
        const float v110 = row11[x0], v111 = row11[x1];

        const float ux = 1.0f - tfx, uy = 1.0f - tfy, uz = 1.0f - tfz;
        const float c00 = v000 * ux + v001 * tfx;
        const float c01 = v010 * ux + v011 * tfx;
        const float c10 = v100 * ux + v101 * tfx;
        const float c11 = v110 * ux + v111 * tfx;
        const float c0 = c00 * uy + c01 * tfy;
        const float c1 = c10 * uy + c11 * tfy;
        acc += c0 * uz + c1 * tfz;
    }

    __shared__ float sm[4][8][8];
    sm[tz][ty][tx] = acc;
    __syncthreads();
    if (tz == 0) {
        out[(b << 16) | (i << 8) | j] =
            sm[0][ty][tx] + sm[1][ty][tx] + sm[2][ty][tx] + sm[3][ty][tx];
    }
}

// ---------------- launch ----------------

extern "C" void kernel_launch(void* const* d_in, const int* in_sizes, int n_in,
                              void* d_out, int out_size, void* d_ws, size_t ws_size,
                              hipStream_t stream) {
    const float* vol = (const float*)d_in[0];
    const float* quats = (const float*)d_in[1];
    float* out = (float*)d_out;

    const int B = in_sizes[1] / 4;  // quaternions: (B,4)
    const size_t nvox = (size_t)NN * NN * NN;
    const size_t need = nvox * sizeof(uint2);   // 134 MB

    dim3 grid(NN / 8, NN / 8, B);
    dim3 block(256, 1, 1);

    if (ws_size >= need) {
        uint2* v4 = (uint2*)d_ws;
        const int pack_blocks = (int)(nvox / 4 / 256);
        hipLaunchKernelGGL(pack4h_kernel, dim3(pack_blocks), dim3(256), 0, stream,
                           vol, v4);
        hipLaunchKernelGGL(rotproj4h_kernel, grid, block, 0, stream, v4, quats, out);
    } else {
        hipLaunchKernelGGL(rotproj_direct_kernel, grid, block, 0, stream,
                           vol, quats, out);
    }
}